// Round 3
// baseline (258.956 us; speedup 1.0000x reference)
//
#include <hip/hip_runtime.h>

#define NN      131072
#define H       256
#define PPATHS  32768
#define LMAX    16
#define EF      8
#define FF      16
#define KP      288        // padded K: 256 pe + 8 edge + 16 scal + 8 zero
#define TPB     32         // paths per block (fused kernel)
#define FS      296        // feat LDS row stride in ushorts (592 B: 16B-aligned)
#define NTHR    320        // 4 gather/GEMM waves + 1 streamer wave

typedef short v8s __attribute__((ext_vector_type(8)));
typedef float v4f __attribute__((ext_vector_type(4)));

__device__ __forceinline__ unsigned short f2bf(float x) {
    unsigned int u = __float_as_uint(x);
    u += 0x7fffu + ((u >> 16) & 1u);     // round-to-nearest-even
    return (unsigned short)(u >> 16);
}

// blocks [0,288): W1T[n][k] = bf16(W1[orig(k)][n]) (k>=280 -> 0)
// blocks [288,352): cvec[j] = b1[j] + sum_{k<512} concat(src,dst)[k]*W1[k][j]
__global__ __launch_bounds__(256) void prep_kernel(
        const float* __restrict__ node_embs,
        const float* __restrict__ W1,
        const float* __restrict__ b1,
        const int*   __restrict__ si,
        const int*   __restrict__ di,
        unsigned short* __restrict__ W1T,
        float*       __restrict__ cvec) {
    __shared__ float red[256];
    const int b = blockIdx.x;
    if (b < KP) {
        const int k = b, n = threadIdx.x;
        float v = 0.0f;
        if (k < 256)      v = W1[(size_t)(512 + k) * H + n];
        else if (k < 280) v = W1[(size_t)(768 + (k - 256)) * H + n];
        W1T[(size_t)n * KP + k] = f2bf(v);
    } else {
        const int jb = b - KP;             // 0..63
        const int t  = threadIdx.x;
        const int jl = t & 3, kp = t >> 2;
        const int j  = jb * 4 + jl;
        const float* src = node_embs + (size_t)si[0] * H;
        const float* dst = node_embs + (size_t)di[0] * H;
        float c = 0.0f;
        #pragma unroll
        for (int i = 0; i < 8; ++i) {
            int k = kp + i * 64;
            float f = (k < H) ? src[k] : dst[k - H];
            c += f * W1[(size_t)k * H + j];
        }
        red[t] = c;
        __syncthreads();
        for (int s = 128; s >= 4; s >>= 1) {
            if (t < s) red[t] += red[t + s];
            __syncthreads();
        }
        if (t < 4) cvec[jb * 4 + t] = b1[jb * 4 + t] + red[t];
    }
}

// Fused: block = 32 paths, 5 waves. Wave 4 = STREAMER: sequentially reads
// this block's 131 KB slice of node_embs (1024 resident blocks cover the
// whole 134 MB table in ~one streaming pass) purely to pull lines into
// L2/L3, converting the gather waves' cold HBM misses (~900 cyc) into
// cache hits (~400 cyc). Independent wave => independent vmcnt => no
// serialization with the gathers (a same-wave warm prologue would drain
// in-order before the first gather). Waves 0-3: Phase A gather (8 paths
// each) -> LDS bf16 feat tile; Phase B: MFMA GEMM + relu/W2/reduce.
__global__ __launch_bounds__(NTHR, 5) void fused_kernel(
        const float* __restrict__ node_embs,
        const int*   __restrict__ path_nodes,
        const int*   __restrict__ path_lens,
        const float* __restrict__ edge_f,
        const float* __restrict__ scal_f,
        const unsigned short* __restrict__ W1T,
        const float* __restrict__ cvec,
        const float* __restrict__ W2,
        const float* __restrict__ b2,
        float*       __restrict__ out) {
    __shared__ __align__(16) unsigned short feat[TPB * FS];   // 18.94 KB
    __shared__ float qpart[TPB][5];

    const int tid  = threadIdx.x;
    const int wave = tid >> 6, lane = tid & 63;
    const int pb   = blockIdx.x * TPB;

    if (wave == 4) {
        // ---- streamer: 8192 float4 per block = 128 float4 per lane ----
        const float4* wp = (const float4*)node_embs + (size_t)blockIdx.x * 8192 + lane;
        float4 wa = make_float4(0, 0, 0, 0);
        #pragma unroll 8
        for (int i = 0; i < 128; ++i) {
            const float4 v = wp[i * 64];
            wa.x += v.x; wa.y += v.y; wa.z += v.z; wa.w += v.w;
        }
        asm volatile("" :: "v"(wa.x), "v"(wa.y), "v"(wa.z), "v"(wa.w));
    } else {
        // cols 256..287: edge, scalar, zero pad
        for (int i = tid; i < TPB * 32; i += 256) {
            const int p = i >> 5, s = i & 31;
            float v = 0.0f;
            if (s < EF)           v = edge_f[(size_t)(pb + p) * EF + s];
            else if (s < EF + FF) v = scal_f[(size_t)(pb + p) * FF + (s - EF)];
            feat[p * FS + H + s] = f2bf(v);
        }

        // Phase A: gather + mean, wave w handles paths [8w, 8w+8)
        for (int pi = 0; pi < 8; ++pi) {
            const int p   = wave * 8 + pi;
            const int gp  = pb + p;
            const int len = path_lens[gp];
            const int iv  = path_nodes[(size_t)gp * LMAX + (lane & 15)];

            float4 a0 = make_float4(0, 0, 0, 0), a1 = make_float4(0, 0, 0, 0);
            float4 a2 = make_float4(0, 0, 0, 0), a3 = make_float4(0, 0, 0, 0);
            int l = 0;
            for (; l + 3 < len; l += 4) {
                const int n0 = __shfl(iv, l);
                const int n1 = __shfl(iv, l + 1);
                const int n2 = __shfl(iv, l + 2);
                const int n3 = __shfl(iv, l + 3);
                const float4 v0 = ((const float4*)(node_embs + (size_t)n0 * H))[lane];
                const float4 v1 = ((const float4*)(node_embs + (size_t)n1 * H))[lane];
                const float4 v2 = ((const float4*)(node_embs + (size_t)n2 * H))[lane];
                const float4 v3 = ((const float4*)(node_embs + (size_t)n3 * H))[lane];
                a0.x += v0.x; a0.y += v0.y; a0.z += v0.z; a0.w += v0.w;
                a1.x += v1.x; a1.y += v1.y; a1.z += v1.z; a1.w += v1.w;
                a2.x += v2.x; a2.y += v2.y; a2.z += v2.z; a2.w += v2.w;
                a3.x += v3.x; a3.y += v3.y; a3.z += v3.z; a3.w += v3.w;
            }
            for (; l < len; ++l) {
                const int n0 = __shfl(iv, l);
                const float4 v0 = ((const float4*)(node_embs + (size_t)n0 * H))[lane];
                a0.x += v0.x; a0.y += v0.y; a0.z += v0.z; a0.w += v0.w;
            }
            const float inv = 1.0f / (float)max(len, 1);
            ushort4 r;
            r.x = f2bf((a0.x + a1.x + a2.x + a3.x) * inv);
            r.y = f2bf((a0.y + a1.y + a2.y + a3.y) * inv);
            r.z = f2bf((a0.z + a1.z + a2.z + a3.z) * inv);
            r.w = f2bf((a0.w + a1.w + a2.w + a3.w) * inv);
            *(ushort4*)&feat[p * FS + 4 * lane] = r;     // 8B aligned
        }
    }
    __syncthreads();

    if (wave < 4) {
        // Phase B: MFMA GEMM. wave w owns cols n in [64w, 64w+64).
        const int col = lane & 15, quad = lane >> 4;
        const int n0  = wave * 64;

        v4f acc[2][4];
        float w2v[4];
        #pragma unroll
        for (int nt = 0; nt < 4; ++nt) {
            const float cv = cvec[n0 + nt * 16 + col];
            w2v[nt] = W2[n0 + nt * 16 + col];
            #pragma unroll
            for (int mt = 0; mt < 2; ++mt)
                acc[mt][nt] = (v4f){cv, cv, cv, cv};
        }

        // A-frag: lane holds feat[mt*16 + col][k0 + quad*8 + j]  (LDS)
        // B-frag: lane holds W1T [n0 + nt*16 + col][k0 + quad*8 + j]
        const unsigned short* Alds  = feat + col * FS + quad * 8;
        const unsigned short* Bbase = W1T + (size_t)(n0 + col) * KP + quad * 8;

        for (int k0 = 0; k0 < KP; k0 += 32) {
            v8s a[2], b[4];
            #pragma unroll
            for (int mt = 0; mt < 2; ++mt)
                a[mt] = *(const v8s*)(Alds + mt * 16 * FS + k0);
            #pragma unroll
            for (int nt = 0; nt < 4; ++nt)
                b[nt] = *(const v8s*)(Bbase + (size_t)(nt * 16) * KP + k0);
            #pragma unroll
            for (int mt = 0; mt < 2; ++mt)
                #pragma unroll
                for (int nt = 0; nt < 4; ++nt)
                    acc[mt][nt] = __builtin_amdgcn_mfma_f32_16x16x32_bf16(
                                      a[mt], b[nt], acc[mt][nt], 0, 0, 0);
        }

        // Epilogue: relu * W2, reduce wave's 64 cols; C/D: col=lane&15, row=quad*4+r
        #pragma unroll
        for (int mt = 0; mt < 2; ++mt) {
            float s[4];
            #pragma unroll
            for (int r = 0; r < 4; ++r) {
                float v = 0.0f;
                #pragma unroll
                for (int nt = 0; nt < 4; ++nt)
                    v += fmaxf(acc[mt][nt][r], 0.0f) * w2v[nt];
                s[r] = v;
            }
            #pragma unroll
            for (int off = 1; off < 16; off <<= 1) {
                #pragma unroll
                for (int r = 0; r < 4; ++r)
                    s[r] += __shfl_xor(s[r], off);
            }
            if (col == 0) {
                #pragma unroll
                for (int r = 0; r < 4; ++r)
                    qpart[mt * 16 + quad * 4 + r][wave] = s[r];
            }
        }
    }
    __syncthreads();

    if (tid < TPB) {
        const float q = qpart[tid][0] + qpart[tid][1] + qpart[tid][2] + qpart[tid][3] + b2[0];
        out[pb + tid] = (path_lens[pb + tid] > 0) ? q : 0.0f;
    }
}

extern "C" void kernel_launch(void* const* d_in, const int* in_sizes, int n_in,
                              void* d_out, int out_size, void* d_ws, size_t ws_size,
                              hipStream_t stream) {
    const float* node_embs  = (const float*)d_in[0];
    const int*   path_nodes = (const int*)d_in[1];
    const int*   path_lens  = (const int*)d_in[2];
    const float* edge_f     = (const float*)d_in[3];
    const float* scal_f     = (const float*)d_in[4];
    const float* W1         = (const float*)d_in[5];
    const float* b1         = (const float*)d_in[6];
    const float* W2         = (const float*)d_in[7];
    const float* b2         = (const float*)d_in[8];
    const int*   si         = (const int*)d_in[9];
    const int*   di         = (const int*)d_in[10];
    float* out = (float*)d_out;

    // workspace: cvec (1 KB) | W1T (147456 B)
    float*          cvec = (float*)d_ws;
    unsigned short* W1T  = (unsigned short*)((char*)d_ws + 1024);

    hipLaunchKernelGGL(prep_kernel, dim3(KP + 64), dim3(256), 0, stream,
                       node_embs, W1, b1, si, di, W1T, cvec);
    hipLaunchKernelGGL(fused_kernel, dim3(PPATHS / TPB), dim3(NTHR), 0, stream,
                       node_embs, path_nodes, path_lens, edge_f, scal_f,
                       W1T, cvec, W2, b2, out);
}

// Round 4
// 258.242 us; speedup vs baseline: 1.0028x; 1.0028x over previous
//
#include <hip/hip_runtime.h>

#define NN      131072
#define H       256
#define PPATHS  32768
#define LMAX    16
#define EF      8
#define FF      16
#define KP      288        // padded K: 256 pe + 8 edge + 16 scal + 8 zero
#define TPB     32         // paths per block
#define FS      296        // feat LDS row stride in ushorts (592 B)

// dynamic LDS layout
#define STAGE_BYTES (4 * 2 * 16 * 1024)            // 4 waves x 2 bufs x 16 rows x 1KB = 131072
#define FEAT_OFF    STAGE_BYTES                    // 18944 B
#define QPART_OFF   (FEAT_OFF + TPB * FS * 2)      // 150016
#define SMEM_BYTES  (QPART_OFF + TPB * 5 * 4)      // 150656 (< 160 KiB)

typedef short v8s __attribute__((ext_vector_type(8)));
typedef float v4f __attribute__((ext_vector_type(4)));

__device__ __forceinline__ unsigned short f2bf(float x) {
    unsigned int u = __float_as_uint(x);
    u += 0x7fffu + ((u >> 16) & 1u);     // round-to-nearest-even
    return (unsigned short)(u >> 16);
}

// blocks [0,288): W1T[n][k] = bf16(W1[orig(k)][n]) (k>=280 -> 0)
// blocks [288,352): cvec[j] = b1[j] + sum_{k<512} concat(src,dst)[k]*W1[k][j]
__global__ __launch_bounds__(256) void prep_kernel(
        const float* __restrict__ node_embs,
        const float* __restrict__ W1,
        const float* __restrict__ b1,
        const int*   __restrict__ si,
        const int*   __restrict__ di,
        unsigned short* __restrict__ W1T,
        float*       __restrict__ cvec) {
    __shared__ float red[256];
    const int b = blockIdx.x;
    if (b < KP) {
        const int k = b, n = threadIdx.x;
        float v = 0.0f;
        if (k < 256)      v = W1[(size_t)(512 + k) * H + n];
        else if (k < 280) v = W1[(size_t)(768 + (k - 256)) * H + n];
        W1T[(size_t)n * KP + k] = f2bf(v);
    } else {
        const int jb = b - KP;             // 0..63
        const int t  = threadIdx.x;
        const int jl = t & 3, kp = t >> 2;
        const int j  = jb * 4 + jl;
        const float* src = node_embs + (size_t)si[0] * H;
        const float* dst = node_embs + (size_t)di[0] * H;
        float c = 0.0f;
        #pragma unroll
        for (int i = 0; i < 8; ++i) {
            int k = kp + i * 64;
            float f = (k < H) ? src[k] : dst[k - H];
            c += f * W1[(size_t)k * H + j];
        }
        red[t] = c;
        __syncthreads();
        for (int s = 128; s >= 4; s >>= 1) {
            if (t < s) red[t] += red[t + s];
            __syncthreads();
        }
        if (t < 4) cvec[jb * 4 + t] = b1[jb * 4 + t] + red[t];
    }
}

// Issue one path's 16 row-DMAs into an LDS buffer. Always 16 (l >= len pads
// target row 0, hot in every cache) so vmcnt counts are STATIC -> a true
// 2-path-deep pipeline via s_waitcnt vmcnt(16). LDS dest is wave-uniform
// row base; HW scatters lane i's 16B to base + i*16 (== linear row copy).
__device__ __forceinline__ void issue_path(const float* __restrict__ ne,
                                           float* sbuf, int ivv, int lenS, int lane) {
    #pragma unroll
    for (int l = 0; l < 16; ++l) {
        const int n  = __builtin_amdgcn_readlane(ivv, l);   // uniform (SGPR)
        const int nn = (l < lenS) ? n : 0;                  // uniform select
        const float* g = ne + (size_t)nn * H + lane * 4;
        __builtin_amdgcn_global_load_lds(
            (const __attribute__((address_space(1))) void*)g,
            (__attribute__((address_space(3))) void*)(sbuf + l * 256),
            16, 0, 0);
    }
}

__device__ __forceinline__ void consume_path(const float* sbuf, int lenS, int lane,
                                             unsigned short* featrow) {
    float4 a = make_float4(0, 0, 0, 0);
    for (int l = 0; l < lenS; ++l) {
        const float4 v = *(const float4*)(sbuf + l * 256 + lane * 4);
        a.x += v.x; a.y += v.y; a.z += v.z; a.w += v.w;
    }
    const float inv = 1.0f / (float)max(lenS, 1);
    ushort4 r;
    r.x = f2bf(a.x * inv);
    r.y = f2bf(a.y * inv);
    r.z = f2bf(a.z * inv);
    r.w = f2bf(a.w * inv);
    *(ushort4*)(featrow + 4 * lane) = r;     // 8B aligned
}

// Fused: block = 32 paths, 4 waves, 147 KB dynamic LDS (1 block/CU).
// Phase A: per wave, 8 paths gathered via global_load_lds double-buffered
// pipeline (16-32 KB guaranteed in flight per wave vs ~4 KB for the VGPR
// gather -- probes the request-depth theory directly). Phase B: MFMA GEMM
// + relu/W2/reduce epilogue, unchanged.
__global__ __launch_bounds__(256, 1) void fused_kernel(
        const float* __restrict__ node_embs,
        const int*   __restrict__ path_nodes,
        const int*   __restrict__ path_lens,
        const float* __restrict__ edge_f,
        const float* __restrict__ scal_f,
        const unsigned short* __restrict__ W1T,
        const float* __restrict__ cvec,
        const float* __restrict__ W2,
        const float* __restrict__ b2,
        float*       __restrict__ out) {
    extern __shared__ __align__(16) char smem[];
    float*          stage = (float*)smem;                       // wave: +8192 f, buf: +4096 f
    unsigned short* feat  = (unsigned short*)(smem + FEAT_OFF);
    float*          qpart = (float*)(smem + QPART_OFF);         // [TPB][5]

    const int tid  = threadIdx.x;
    const int wave = tid >> 6, lane = tid & 63;
    const int pb   = blockIdx.x * TPB;

    // cols 256..287: edge, scalar, zero pad
    for (int i = tid; i < TPB * 32; i += 256) {
        const int p = i >> 5, s = i & 31;
        float v = 0.0f;
        if (s < EF)           v = edge_f[(size_t)(pb + p) * EF + s];
        else if (s < EF + FF) v = scal_f[(size_t)(pb + p) * FF + (s - EF)];
        feat[p * FS + H + s] = f2bf(v);
    }

    // ---- Phase A: DMA-pipelined gather, wave w owns paths [8w, 8w+8) ----
    int lens[8], ivr[8];
    #pragma unroll
    for (int pi = 0; pi < 8; ++pi) {
        const int gp = pb + wave * 8 + pi;
        lens[pi] = __builtin_amdgcn_readfirstlane(path_lens[gp]);
        ivr[pi]  = path_nodes[(size_t)gp * LMAX + (lane & 15)];
    }
    float* sb0 = stage + wave * 8192;
    float* sb1 = sb0 + 4096;

    // clean vmcnt slate so static counts below are exact
    asm volatile("s_waitcnt vmcnt(0)" ::: "memory");
    issue_path(node_embs, sb0, ivr[0], lens[0], lane);
    issue_path(node_embs, sb1, ivr[1], lens[1], lane);
    #pragma unroll
    for (int pi = 0; pi < 8; ++pi) {
        if (pi < 7) { asm volatile("s_waitcnt vmcnt(16)" ::: "memory"); }
        else        { asm volatile("s_waitcnt vmcnt(0)"  ::: "memory"); }
        __builtin_amdgcn_sched_barrier(0);
        float* sb = (pi & 1) ? sb1 : sb0;
        consume_path(sb, lens[pi], lane, feat + (wave * 8 + pi) * FS);
        __builtin_amdgcn_sched_barrier(0);
        if (pi + 2 < 8)
            issue_path(node_embs, sb, ivr[pi + 2], lens[pi + 2], lane);
    }
    __syncthreads();

    // ---- Phase B: MFMA GEMM. wave w owns cols n in [64w, 64w+64) ----
    const int col = lane & 15, quad = lane >> 4;
    const int n0  = wave * 64;

    v4f acc[2][4];
    float w2v[4];
    #pragma unroll
    for (int nt = 0; nt < 4; ++nt) {
        const float cv = cvec[n0 + nt * 16 + col];
        w2v[nt] = W2[n0 + nt * 16 + col];
        #pragma unroll
        for (int mt = 0; mt < 2; ++mt)
            acc[mt][nt] = (v4f){cv, cv, cv, cv};
    }

    const unsigned short* Alds  = feat + col * FS + quad * 8;
    const unsigned short* Bbase = W1T + (size_t)(n0 + col) * KP + quad * 8;

    for (int k0 = 0; k0 < KP; k0 += 32) {
        v8s a[2], b[4];
        #pragma unroll
        for (int mt = 0; mt < 2; ++mt)
            a[mt] = *(const v8s*)(Alds + mt * 16 * FS + k0);
        #pragma unroll
        for (int nt = 0; nt < 4; ++nt)
            b[nt] = *(const v8s*)(Bbase + (size_t)(nt * 16) * KP + k0);
        #pragma unroll
        for (int mt = 0; mt < 2; ++mt)
            #pragma unroll
            for (int nt = 0; nt < 4; ++nt)
                acc[mt][nt] = __builtin_amdgcn_mfma_f32_16x16x32_bf16(
                                  a[mt], b[nt], acc[mt][nt], 0, 0, 0);
    }

    #pragma unroll
    for (int mt = 0; mt < 2; ++mt) {
        float s[4];
        #pragma unroll
        for (int r = 0; r < 4; ++r) {
            float v = 0.0f;
            #pragma unroll
            for (int nt = 0; nt < 4; ++nt)
                v += fmaxf(acc[mt][nt][r], 0.0f) * w2v[nt];
            s[r] = v;
        }
        #pragma unroll
        for (int off = 1; off < 16; off <<= 1) {
            #pragma unroll
            for (int r = 0; r < 4; ++r)
                s[r] += __shfl_xor(s[r], off);
        }
        if (col == 0) {
            #pragma unroll
            for (int r = 0; r < 4; ++r)
                qpart[(mt * 16 + quad * 4 + r) * 5 + wave] = s[r];
        }
    }
    __syncthreads();

    if (tid < TPB) {
        const float q = qpart[tid * 5 + 0] + qpart[tid * 5 + 1]
                      + qpart[tid * 5 + 2] + qpart[tid * 5 + 3] + b2[0];
        out[pb + tid] = (path_lens[pb + tid] > 0) ? q : 0.0f;
    }
}

extern "C" void kernel_launch(void* const* d_in, const int* in_sizes, int n_in,
                              void* d_out, int out_size, void* d_ws, size_t ws_size,
                              hipStream_t stream) {
    const float* node_embs  = (const float*)d_in[0];
    const int*   path_nodes = (const int*)d_in[1];
    const int*   path_lens  = (const int*)d_in[2];
    const float* edge_f     = (const float*)d_in[3];
    const float* scal_f     = (const float*)d_in[4];
    const float* W1         = (const float*)d_in[5];
    const float* b1         = (const float*)d_in[6];
    const float* W2         = (const float*)d_in[7];
    const float* b2         = (const float*)d_in[8];
    const int*   si         = (const int*)d_in[9];
    const int*   di         = (const int*)d_in[10];
    float* out = (float*)d_out;

    // workspace: cvec (1 KB) | W1T (147456 B)
    float*          cvec = (float*)d_ws;
    unsigned short* W1T  = (unsigned short*)((char*)d_ws + 1024);

    hipFuncSetAttribute((const void*)fused_kernel,
                        hipFuncAttributeMaxDynamicSharedMemorySize, SMEM_BYTES);

    hipLaunchKernelGGL(prep_kernel, dim3(KP + 64), dim3(256), 0, stream,
                       node_embs, W1, b1, si, di, W1T, cvec);
    hipLaunchKernelGGL(fused_kernel, dim3(PPATHS / TPB), dim3(256), SMEM_BYTES, stream,
                       node_embs, path_nodes, path_lens, edge_f, scal_f,
                       W1T, cvec, W2, b2, out);
}

// Round 5
// 233.548 us; speedup vs baseline: 1.1088x; 1.1057x over previous
//
#include <hip/hip_runtime.h>

#define NN      131072
#define H       256
#define PPATHS  32768
#define LMAX    16
#define EF      8
#define FF      16
#define KP      288        // padded K: 256 pe + 8 edge + 16 scal + 8 zero
#define TPB     32         // paths per block (fused kernel)
#define FS      296        // feat LDS row stride in ushorts (592 B: 16B-aligned)

typedef short v8s __attribute__((ext_vector_type(8)));
typedef float v4f __attribute__((ext_vector_type(4)));

__device__ __forceinline__ unsigned short f2bf(float x) {
    unsigned int u = __float_as_uint(x);
    u += 0x7fffu + ((u >> 16) & 1u);     // round-to-nearest-even
    return (unsigned short)(u >> 16);
}

// blocks [0,288): W1T[n][k] = bf16(W1[orig(k)][n]) (k>=280 -> 0)
// blocks [288,352): cvec[j] = b1[j] + sum_{k<512} concat(src,dst)[k]*W1[k][j]
__global__ __launch_bounds__(256) void prep_kernel(
        const float* __restrict__ node_embs,
        const float* __restrict__ W1,
        const float* __restrict__ b1,
        const int*   __restrict__ si,
        const int*   __restrict__ di,
        unsigned short* __restrict__ W1T,
        float*       __restrict__ cvec) {
    __shared__ float red[256];
    const int b = blockIdx.x;
    if (b < KP) {
        const int k = b, n = threadIdx.x;
        float v = 0.0f;
        if (k < 256)      v = W1[(size_t)(512 + k) * H + n];
        else if (k < 280) v = W1[(size_t)(768 + (k - 256)) * H + n];
        W1T[(size_t)n * KP + k] = f2bf(v);
    } else {
        const int jb = b - KP;             // 0..63
        const int t  = threadIdx.x;
        const int jl = t & 3, kp = t >> 2;
        const int j  = jb * 4 + jl;
        const float* src = node_embs + (size_t)si[0] * H;
        const float* dst = node_embs + (size_t)di[0] * H;
        float c = 0.0f;
        #pragma unroll
        for (int i = 0; i < 8; ++i) {
            int k = kp + i * 64;
            float f = (k < H) ? src[k] : dst[k - H];
            c += f * W1[(size_t)k * H + j];
        }
        red[t] = c;
        __syncthreads();
        for (int s = 128; s >= 4; s >>= 1) {
            if (t < s) red[t] += red[t + s];
            __syncthreads();
        }
        if (t < 4) cvec[jb * 4 + t] = b1[jb * 4 + t] + red[t];
    }
}

// Fused: block = 32 paths. Phase A: 4 waves gather 8 paths each -> LDS bf16
// feat tile. Phase B: MFMA GEMM, A-frags from LDS, B-frags from L2-resident
// W1T; fused relu/W2/reduce epilogue. No feat global round-trip.
// NOTE (R0-R4 exploration): the gather is pinned at ~14 rows/us/CU across
// ILP 1..32-deep, occupancy 3..22 waves/CU, DMA vs VGPR paths, warm vs cold
// table -- a shared random-line service wall (~3.7 TB/s chip-wide), with
// FETCH already = one table pass. This config is the measured optimum.
__global__ __launch_bounds__(256, 4) void fused_kernel(
        const float* __restrict__ node_embs,
        const int*   __restrict__ path_nodes,
        const int*   __restrict__ path_lens,
        const float* __restrict__ edge_f,
        const float* __restrict__ scal_f,
        const unsigned short* __restrict__ W1T,
        const float* __restrict__ cvec,
        const float* __restrict__ W2,
        const float* __restrict__ b2,
        float*       __restrict__ out) {
    __shared__ __align__(16) unsigned short feat[TPB * FS];   // 18.94 KB
    __shared__ float qpart[TPB][5];

    const int tid  = threadIdx.x;
    const int wave = tid >> 6, lane = tid & 63;
    const int pb   = blockIdx.x * TPB;

    // cols 256..287: edge, scalar, zero pad (issued first so loads fly early)
    for (int i = tid; i < TPB * 32; i += 256) {
        const int p = i >> 5, s = i & 31;
        float v = 0.0f;
        if (s < EF)           v = edge_f[(size_t)(pb + p) * EF + s];
        else if (s < EF + FF) v = scal_f[(size_t)(pb + p) * FF + (s - EF)];
        feat[p * FS + H + s] = f2bf(v);
    }

    // Phase A: gather + mean, wave w handles paths [8w, 8w+8)
    for (int pi = 0; pi < 8; ++pi) {
        const int p   = wave * 8 + pi;
        const int gp  = pb + p;
        const int len = path_lens[gp];
        const int iv  = path_nodes[(size_t)gp * LMAX + (lane & 15)];

        float4 a0 = make_float4(0, 0, 0, 0), a1 = make_float4(0, 0, 0, 0);
        float4 a2 = make_float4(0, 0, 0, 0), a3 = make_float4(0, 0, 0, 0);
        int l = 0;
        for (; l + 3 < len; l += 4) {
            const int n0 = __shfl(iv, l);
            const int n1 = __shfl(iv, l + 1);
            const int n2 = __shfl(iv, l + 2);
            const int n3 = __shfl(iv, l + 3);
            const float4 v0 = ((const float4*)(node_embs + (size_t)n0 * H))[lane];
            const float4 v1 = ((const float4*)(node_embs + (size_t)n1 * H))[lane];
            const float4 v2 = ((const float4*)(node_embs + (size_t)n2 * H))[lane];
            const float4 v3 = ((const float4*)(node_embs + (size_t)n3 * H))[lane];
            a0.x += v0.x; a0.y += v0.y; a0.z += v0.z; a0.w += v0.w;
            a1.x += v1.x; a1.y += v1.y; a1.z += v1.z; a1.w += v1.w;
            a2.x += v2.x; a2.y += v2.y; a2.z += v2.z; a2.w += v2.w;
            a3.x += v3.x; a3.y += v3.y; a3.z += v3.z; a3.w += v3.w;
        }
        for (; l < len; ++l) {
            const int n0 = __shfl(iv, l);
            const float4 v0 = ((const float4*)(node_embs + (size_t)n0 * H))[lane];
            a0.x += v0.x; a0.y += v0.y; a0.z += v0.z; a0.w += v0.w;
        }
        const float inv = 1.0f / (float)max(len, 1);
        ushort4 r;
        r.x = f2bf((a0.x + a1.x + a2.x + a3.x) * inv);
        r.y = f2bf((a0.y + a1.y + a2.y + a3.y) * inv);
        r.z = f2bf((a0.z + a1.z + a2.z + a3.z) * inv);
        r.w = f2bf((a0.w + a1.w + a2.w + a3.w) * inv);
        *(ushort4*)&feat[p * FS + 4 * lane] = r;     // 8B aligned
    }
    __syncthreads();

    // Phase B: MFMA GEMM. wave w owns cols n in [64w, 64w+64).
    const int col = lane & 15, quad = lane >> 4;
    const int n0  = wave * 64;

    v4f acc[2][4];
    float w2v[4];
    #pragma unroll
    for (int nt = 0; nt < 4; ++nt) {
        const float cv = cvec[n0 + nt * 16 + col];
        w2v[nt] = W2[n0 + nt * 16 + col];
        #pragma unroll
        for (int mt = 0; mt < 2; ++mt)
            acc[mt][nt] = (v4f){cv, cv, cv, cv};
    }

    // A-frag: lane holds feat[mt*16 + col][k0 + quad*8 + j]  (LDS, 16B contig)
    // B-frag: lane holds W1T [n0 + nt*16 + col][k0 + quad*8 + j]
    const unsigned short* Alds  = feat + col * FS + quad * 8;
    const unsigned short* Bbase = W1T + (size_t)(n0 + col) * KP + quad * 8;

    for (int k0 = 0; k0 < KP; k0 += 32) {
        v8s a[2], b[4];
        #pragma unroll
        for (int mt = 0; mt < 2; ++mt)
            a[mt] = *(const v8s*)(Alds + mt * 16 * FS + k0);
        #pragma unroll
        for (int nt = 0; nt < 4; ++nt)
            b[nt] = *(const v8s*)(Bbase + (size_t)(nt * 16) * KP + k0);
        #pragma unroll
        for (int mt = 0; mt < 2; ++mt)
            #pragma unroll
            for (int nt = 0; nt < 4; ++nt)
                acc[mt][nt] = __builtin_amdgcn_mfma_f32_16x16x32_bf16(
                                  a[mt], b[nt], acc[mt][nt], 0, 0, 0);
    }

    // Epilogue: relu * W2, reduce this wave's 64 cols; C/D: col=lane&15, row=quad*4+r
    #pragma unroll
    for (int mt = 0; mt < 2; ++mt) {
        float s[4];
        #pragma unroll
        for (int r = 0; r < 4; ++r) {
            float v = 0.0f;
            #pragma unroll
            for (int nt = 0; nt < 4; ++nt)
                v += fmaxf(acc[mt][nt][r], 0.0f) * w2v[nt];
            s[r] = v;
        }
        #pragma unroll
        for (int off = 1; off < 16; off <<= 1) {
            #pragma unroll
            for (int r = 0; r < 4; ++r)
                s[r] += __shfl_xor(s[r], off);
        }
        if (col == 0) {
            #pragma unroll
            for (int r = 0; r < 4; ++r)
                qpart[mt * 16 + quad * 4 + r][wave] = s[r];
        }
    }
    __syncthreads();

    if (tid < TPB) {
        const float q = qpart[tid][0] + qpart[tid][1] + qpart[tid][2] + qpart[tid][3] + b2[0];
        out[pb + tid] = (path_lens[pb + tid] > 0) ? q : 0.0f;
    }
}

extern "C" void kernel_launch(void* const* d_in, const int* in_sizes, int n_in,
                              void* d_out, int out_size, void* d_ws, size_t ws_size,
                              hipStream_t stream) {
    const float* node_embs  = (const float*)d_in[0];
    const int*   path_nodes = (const int*)d_in[1];
    const int*   path_lens  = (const int*)d_in[2];
    const float* edge_f     = (const float*)d_in[3];
    const float* scal_f     = (const float*)d_in[4];
    const float* W1         = (const float*)d_in[5];
    const float* b1         = (const float*)d_in[6];
    const float* W2         = (const float*)d_in[7];
    const float* b2         = (const float*)d_in[8];
    const int*   si         = (const int*)d_in[9];
    const int*   di         = (const int*)d_in[10];
    float* out = (float*)d_out;

    // workspace: cvec (1 KB) | W1T (147456 B)
    float*          cvec = (float*)d_ws;
    unsigned short* W1T  = (unsigned short*)((char*)d_ws + 1024);

    hipLaunchKernelGGL(prep_kernel, dim3(KP + 64), dim3(256), 0, stream,
                       node_embs, W1, b1, si, di, W1T, cvec);
    hipLaunchKernelGGL(fused_kernel, dim3(PPATHS / TPB), dim3(256), 0, stream,
                       node_embs, path_nodes, path_lens, edge_f, scal_f,
                       W1T, cvec, W2, b2, out);
}